// Round 18
// baseline (250.959 us; speedup 1.0000x reference)
//
#include <hip/hip_runtime.h>

#define NB 512
#define ND 32
#define NH 256
#define NSTEPS 8

typedef __attribute__((ext_vector_type(8))) short short8;
typedef __attribute__((ext_vector_type(4))) short short4v;
typedef __attribute__((ext_vector_type(4))) float f32x4;

__device__ __constant__ float Atab[6][5] = {
    {0.f, 0.f, 0.f, 0.f, 0.f},
    {0.2f, 0.f, 0.f, 0.f, 0.f},
    {3.f/40.f, 9.f/40.f, 0.f, 0.f, 0.f},
    {44.f/45.f, -56.f/15.f, 32.f/9.f, 0.f, 0.f},
    {19372.f/6561.f, -25360.f/2187.f, 64448.f/6561.f, -212.f/729.f, 0.f},
    {9017.f/3168.f, -355.f/33.f, 46732.f/5247.f, 49.f/176.f, -5103.f/18656.f}
};
__device__ __constant__ float Btab[6] = {
    35.f/384.f, 0.f, 500.f/1113.f, 125.f/192.f, -2187.f/6784.f, 11.f/84.f
};
__device__ __constant__ float Ctab[6] = {0.f, 0.2f, 0.3f, 0.8f, 8.f/9.f, 1.f};

static __device__ __forceinline__ short f2bf(float f){
    __bf16 h = (__bf16)f;
    return __builtin_bit_cast(short, h);
}
static __device__ __forceinline__ float bf_lo(unsigned p){
    return __builtin_bit_cast(float, p << 16);
}
static __device__ __forceinline__ float bf_hi(unsigned p){
    return __builtin_bit_cast(float, p & 0xffff0000u);
}
static __device__ __forceinline__ float fast_tanh(float x){
    float e = __expf(2.f * x);
    return 1.f - 2.f / (e + 1.f);
}

// XOR-swizzled LDS addressing: row stride 512B, byte ^= (row&7)<<4.
#define SWZ(base, row, byte) ((base) + ((row) << 9) + ((byte) ^ (((row) & 7) << 4)))

// ---- prep: fragment-ordered bf16 W3 into ws ----
// frag(mt,kk), lane l: short8 of W3[kk*32+g*8+e][mt*16+c], at ws[(mt*8+kk)*64+l]
extern "C" __global__ void prep_kernel(const float* __restrict__ W3,
                                       short8* __restrict__ ws)
{
    const int tid = threadIdx.x;
    #pragma unroll
    for (int r = 0; r < 4; ++r) {
        const int idx = r*256 + tid;          // 0..1023
        const int l  = idx & 63;
        const int kk = (idx >> 6) & 7;
        const int mt = idx >> 9;
        const int g = (l >> 4) & 3, c = l & 15;
        short8 v;
        #pragma unroll
        for (int e = 0; e < 8; ++e)
            v[e] = f2bf(W3[(kk*32 + g*8 + e)*ND + mt*16 + c]);
        ws[idx] = v;
    }
}

// One block per batch element; EIGHT waves (512 threads); 2 blocks/CU.
// Each wave owns TWO M-tiles (w2f = 64 regs) -> <=128 regs/wave ->
// 4 waves/SIMD (double the TLP of the 4-wave kernel). Phase bodies are the
// verified R15 forms with wave-decomposition indices j = w*32 + m*16 + ...
extern "C" __global__ void __launch_bounds__(512, 4)
node_kernel(const float* __restrict__ x_in,
            const float* __restrict__ W1, const float* __restrict__ b1,
            const float* __restrict__ W2, const float* __restrict__ b2,
            const float* __restrict__ W3, const float* __restrict__ b3,
            const short8* __restrict__ w3ws,
            float* __restrict__ out)
{
    __shared__ __align__(16) short LAA[33*256];   // A^T rows 0..31 + row32 = h1 (swizzled)
    __shared__ __align__(16) short LTs[33*256];   // Ts^T rows 0..31 + row32 = h2 (swizzled)
    __shared__ __align__(16) short8 W3L[16*64];   // fragment-ordered W3 (16 KB)
    __shared__ __align__(16) unsigned LW1[16*256];// packed bf16-pair W1 columns (16 KB)
    __shared__ __align__(16) float h2pre_s[NH];
    __shared__ __align__(16) float s2_s[NH];
    __shared__ __align__(16) float xs_s[8][ND];   // per-wave private
    __shared__ __align__(16) float xc_s[8][ND];   // per-wave private
    __shared__ __align__(16) float ksb[8][6][ND]; // per-wave private
    __shared__ __align__(16) float b3s[ND];
    __shared__ __align__(16) float w1ts[NH];
    __shared__ __align__(16) float b1s[NH];
    __shared__ __align__(16) float b2s[NH];
    __shared__ float red[8][3];

    const int bid = blockIdx.x;
    const int tid = threadIdx.x;   // 0..511
    const int w = tid >> 6;        // wave id 0..7
    const int l = tid & 63;        // lane
    const int g = (l >> 4) & 3;    // lane group
    const int c = l & 15;          // lane&15

    char* LAc = (char*)LAA;
    char* LTc = (char*)LTs;
    const int swc = (c & 7) << 4;  // read-side swizzle

    // ---- one-time: W2 fragments into registers (2 M-tiles per wave) ----
    // frag (m,kk): value W2[kk*32+g*8+e][w*32+m*16+c]
    short8 w2f[2][8];
    #pragma unroll
    for (int m = 0; m < 2; ++m) {
        const int j = w*32 + m*16 + c;
        #pragma unroll
        for (int kk = 0; kk < 8; ++kk) {
            const int k0 = kk*32 + g*8;
            short8 f;
            #pragma unroll
            for (int e = 0; e < 8; ++e) f[e] = f2bf(W2[(k0+e)*NH + j]);
            w2f[m][kk] = f;
        }
    }
    // ---- one-time: W1 columns packed bf16 + scalars into LDS (tid<256) ----
    if (tid < NH) {
        #pragma unroll
        for (int q = 0; q < 16; ++q) {
            unsigned lo = (unsigned)(unsigned short)f2bf(W1[(2*q)*NH + tid]);
            unsigned hi = (unsigned)(unsigned short)f2bf(W1[(2*q+1)*NH + tid]);
            LW1[q*256 + tid] = lo | (hi << 16);
        }
        w1ts[tid] = W1[32*NH + tid];
        b1s[tid]  = b1[tid];
        b2s[tid]  = b2[tid];
        if (tid < ND) b3s[tid] = b3[tid];
    }
    // ---- one-time: W3 fragments global->LDS ----
    #pragma unroll
    for (int r = 0; r < 2; ++r) W3L[r*512 + tid] = w3ws[r*512 + tid];
    // ---- J-phase tile ids (waves 4..7 mirror 0..3; their jj is discarded) ----
    const int mtJ = (w >> 1) & 1, ntJ = w & 1;

    // ---- init per-wave ODE state ----
    if (l < ND) {
        const float xv = x_in[bid*ND + l];
        xc_s[w][l] = xv;
        xs_s[w][l] = xv;
    }
    __syncthreads();

    const float dt = 0.125f;
    float fr_acc = 0.f, ld_acc = 0.f, vf_acc = 0.f;
    const short8 zfrag = {0,0,0,0,0,0,0,0};

    for (int n = 0; n < NSTEPS; ++n) {
        const float t0 = (float)n * dt;
        for (int sg = 0; sg < 6; ++sg) {
            const float t_eff = 1.0f - (t0 + Ctab[sg]*dt);

            // ---- layer 1 + A-column build: waves 0..3 only (tid<256) ----
            if (w < 4) {
                unsigned w1c[16];
                #pragma unroll
                for (int q = 0; q < 16; ++q) w1c[q] = LW1[q*256 + tid];
                float pre = b1s[tid] + t_eff * w1ts[tid];
                #pragma unroll
                for (int q = 0; q < 8; ++q) {
                    f32x4 xq = *(const f32x4*)&xs_s[w][q*4];   // own-wave broadcast
                    unsigned p0 = w1c[2*q], p1 = w1c[2*q+1];
                    pre += xq[0]*bf_lo(p0) + xq[1]*bf_hi(p0)
                         + xq[2]*bf_lo(p1) + xq[3]*bf_hi(p1);
                }
                const float h1 = fast_tanh(pre);
                const float s1 = 1.f - h1*h1;
                #pragma unroll
                for (int q = 0; q < 16; ++q) {
                    unsigned p = w1c[q];
                    *(short*)SWZ(LAc, 2*q,   2*tid) = f2bf(bf_lo(p)*s1);
                    *(short*)SWZ(LAc, 2*q+1, 2*tid) = f2bf(bf_hi(p)*s1);
                }
                ((short*)LAA)[32*256 + tid] = f2bf(h1);  // row32 (swz==0)
            }
            __syncthreads();   // B1: A ready

            // ---- T^T pass 1: h1 column tile -> h2pre (2 M-tiles/wave) ----
            {
                f32x4 acc2[2];
                #pragma unroll
                for (int m = 0; m < 2; ++m) acc2[m] = (f32x4){0.f,0.f,0.f,0.f};
                #pragma unroll
                for (int kk = 0; kk < 8; ++kk) {
                    const int bo = kk*64 + g*16;
                    short8 fA2 = zfrag;                   // i=32 col: h1 only at c==0
                    if (c == 0) fA2 = *(const short8*)(LAc + (32 << 9) + bo);
                    #pragma unroll
                    for (int m = 0; m < 2; ++m)
                        acc2[m] = __builtin_amdgcn_mfma_f32_16x16x32_bf16(w2f[m][kk], fA2, acc2[m], 0,0,0);
                }
                if (c == 0) {
                    #pragma unroll
                    for (int m = 0; m < 2; ++m)
                        *(f32x4*)&h2pre_s[w*32 + m*16 + g*4] = acc2[m];
                }
            }
            // ---- h2/s2 for this wave's j-range (own-wave LDS, in-order) ----
            if (l < 32) {
                const int j = w*32 + l;
                const float h2 = fast_tanh(h2pre_s[j] + b2s[j]);
                s2_s[j] = 1.f - h2*h2;
                ((short*)LTs)[32*256 + j] = f2bf(h2);     // row32 := h2 (swz==0)
            }

            // ---- T^T pass 2 (fused): tangent tiles, scale & store ----
            {
                f32x4 accT[2][2];
                #pragma unroll
                for (int m = 0; m < 2; ++m) {
                    accT[m][0] = (f32x4){0.f,0.f,0.f,0.f};
                    accT[m][1] = (f32x4){0.f,0.f,0.f,0.f};
                }
                #pragma unroll
                for (int kk = 0; kk < 8; ++kk) {
                    const int bo = kk*64 + g*16;
                    short8 fA0 = *(const short8*)(LAc + (( 0 + c) << 9) + (bo ^ swc));
                    short8 fA1 = *(const short8*)(LAc + ((16 + c) << 9) + (bo ^ swc));
                    #pragma unroll
                    for (int m = 0; m < 2; ++m) {
                        accT[m][0] = __builtin_amdgcn_mfma_f32_16x16x32_bf16(w2f[m][kk], fA0, accT[m][0], 0,0,0);
                        accT[m][1] = __builtin_amdgcn_mfma_f32_16x16x32_bf16(w2f[m][kk], fA1, accT[m][1], 0,0,0);
                    }
                }
                #pragma unroll
                for (int m = 0; m < 2; ++m) {
                    const int j0 = w*32 + m*16 + g*4;
                    f32x4 s2q = *(const f32x4*)&s2_s[j0];     // own-wave broadcast
                    #pragma unroll
                    for (int q = 0; q < 2; ++q) {
                        f32x4 v = accT[m][q] * s2q;
                        short4v p;
                        p[0] = f2bf(v[0]); p[1] = f2bf(v[1]); p[2] = f2bf(v[2]); p[3] = f2bf(v[3]);
                        *(short4v*)SWZ(LTc, q*16 + c, 2*j0) = p;
                    }
                }
            }
            __syncthreads();   // B2: Ts ready

            // ---- J-phase: identical body for all 8 waves (R15-verified form);
            //      waves 4..7's jj is computed but not accumulated ----
            f32x4 jva = (f32x4){0,0,0,0}, jvb = (f32x4){0,0,0,0}, jj = (f32x4){0,0,0,0};
            #pragma unroll
            for (int kk = 0; kk < 8; ++kk) {
                const int bo = kk*64 + g*16;
                short8 w3f0 = W3L[kk*64 + l];         // mt=0
                short8 w3f1 = W3L[(8+kk)*64 + l];     // mt=1
                short8 h2f = zfrag;
                if (c == 0) h2f = *(const short8*)(LTc + (32 << 9) + bo);
                jva = __builtin_amdgcn_mfma_f32_16x16x32_bf16(w3f0, h2f, jva, 0,0,0);
                jvb = __builtin_amdgcn_mfma_f32_16x16x32_bf16(w3f1, h2f, jvb, 0,0,0);
                short8 bJ = *(const short8*)(LTc + ((ntJ*16 + c) << 9) + (bo ^ swc));
                jj = __builtin_amdgcn_mfma_f32_16x16x32_bf16((mtJ == 0) ? w3f0 : w3f1, bJ, jj, 0,0,0);
            }

            const float wB = dt * Btab[sg];
            // ---- vf + per-wave ODE state update (same-wave, no barrier) ----
            if (c == 0) {
                const f32x4 b3a = *(const f32x4*)&b3s[g*4];      // from LDS
                const f32x4 b3b = *(const f32x4*)&b3s[16 + g*4];
                f32x4 dxa, dxb;
                dxa[0] = -(jva[0]+b3a[0]); dxa[1] = -(jva[1]+b3a[1]);
                dxa[2] = -(jva[2]+b3a[2]); dxa[3] = -(jva[3]+b3a[3]);
                dxb[0] = -(jvb[0]+b3b[0]); dxb[1] = -(jvb[1]+b3b[1]);
                dxb[2] = -(jvb[2]+b3b[2]); dxb[3] = -(jvb[3]+b3b[3]);
                *(f32x4*)&ksb[w][sg][g*4]      = dxa;
                *(f32x4*)&ksb[w][sg][16 + g*4] = dxb;
                if (w == 7)   // count vf once
                    vf_acc += wB * (dxa[0]*dxa[0]+dxa[1]*dxa[1]+dxa[2]*dxa[2]+dxa[3]*dxa[3]
                                  + dxb[0]*dxb[0]+dxb[1]*dxb[1]+dxb[2]*dxb[2]+dxb[3]*dxb[3]);
            }
            if (l < ND) {
                if (sg < 5) {
                    float v = xc_s[w][l];
                    for (int q = 0; q <= sg; ++q) v += dt * Atab[sg+1][q] * ksb[w][q][l];
                    xs_s[w][l] = v;
                } else {
                    float v = xc_s[w][l];
                    #pragma unroll
                    for (int q = 0; q < 6; ++q) v += dt * Btab[q] * ksb[w][q][l];
                    xc_s[w][l] = v;
                    xs_s[w][l] = v;
                }
            }
            // ---- frob / trace: only waves 0..3 own J tiles ----
            if (w < 4) {
                fr_acc += wB * (jj[0]*jj[0]+jj[1]*jj[1]+jj[2]*jj[2]+jj[3]*jj[3]);
                if (mtJ == ntJ) {
                    const int dd = c - g*4;
                    if (dd >= 0 && dd < 4) {
                        float da = (dd==0)?jj[0]:(dd==1)?jj[1]:(dd==2)?jj[2]:jj[3];
                        ld_acc -= wB * da;
                    }
                }
            }
        }
    }

    // ---- final reduction of the three integrals ----
    float fr = fr_acc, ld = ld_acc, vf = vf_acc;
    #pragma unroll
    for (int off = 32; off > 0; off >>= 1) {
        fr += __shfl_down(fr, off, 64);
        ld += __shfl_down(ld, off, 64);
        vf += __shfl_down(vf, off, 64);
    }
    if (l == 0) { red[w][0] = fr; red[w][1] = ld; red[w][2] = vf; }
    __syncthreads();
    if (tid == 0) {
        float a = 0.f, b = 0.f, cq = 0.f;
        #pragma unroll
        for (int q = 0; q < 8; ++q) { a += red[q][0]; b += red[q][1]; cq += red[q][2]; }
        out[bid*35 + 32] = b;    // log_det = -∫tr
        out[bid*35 + 33] = cq;   // ∫|dxdt|^2
        out[bid*35 + 34] = a;    // ∫sum(J*J)
    }
    if (w == 7 && l < ND) out[bid*35 + l] = xc_s[7][l];
}

extern "C" void kernel_launch(void* const* d_in, const int* in_sizes, int n_in,
                              void* d_out, int out_size, void* d_ws, size_t ws_size,
                              hipStream_t stream) {
    const float* x  = (const float*)d_in[0];
    const float* W1 = (const float*)d_in[1];
    const float* b1 = (const float*)d_in[2];
    const float* W2 = (const float*)d_in[3];
    const float* b2 = (const float*)d_in[4];
    const float* W3 = (const float*)d_in[5];
    const float* b3 = (const float*)d_in[6];
    float* outp = (float*)d_out;
    hipLaunchKernelGGL(prep_kernel, dim3(1), dim3(256), 0, stream,
                       W3, (short8*)d_ws);
    hipLaunchKernelGGL(node_kernel, dim3(NB), dim3(512), 0, stream,
                       x, W1, b1, W2, b2, W3, b3, (const short8*)d_ws, outp);
}

// Round 19
// 206.492 us; speedup vs baseline: 1.2153x; 1.2153x over previous
//
#include <hip/hip_runtime.h>

#define NB 512
#define ND 32
#define NH 256
#define NSTEPS 8

typedef __attribute__((ext_vector_type(8))) short short8;
typedef __attribute__((ext_vector_type(4))) short short4v;
typedef __attribute__((ext_vector_type(4))) float f32x4;

__device__ __constant__ float Atab[6][5] = {
    {0.f, 0.f, 0.f, 0.f, 0.f},
    {0.2f, 0.f, 0.f, 0.f, 0.f},
    {3.f/40.f, 9.f/40.f, 0.f, 0.f, 0.f},
    {44.f/45.f, -56.f/15.f, 32.f/9.f, 0.f, 0.f},
    {19372.f/6561.f, -25360.f/2187.f, 64448.f/6561.f, -212.f/729.f, 0.f},
    {9017.f/3168.f, -355.f/33.f, 46732.f/5247.f, 49.f/176.f, -5103.f/18656.f}
};
__device__ __constant__ float Btab[6] = {
    35.f/384.f, 0.f, 500.f/1113.f, 125.f/192.f, -2187.f/6784.f, 11.f/84.f
};
__device__ __constant__ float Ctab[6] = {0.f, 0.2f, 0.3f, 0.8f, 8.f/9.f, 1.f};

static __device__ __forceinline__ short f2bf(float f){
    __bf16 h = (__bf16)f;
    return __builtin_bit_cast(short, h);
}
static __device__ __forceinline__ float bf_lo(unsigned p){
    return __builtin_bit_cast(float, p << 16);
}
static __device__ __forceinline__ float bf_hi(unsigned p){
    return __builtin_bit_cast(float, p & 0xffff0000u);
}
static __device__ __forceinline__ float fast_tanh(float x){
    float e = __expf(2.f * x);
    return 1.f - 2.f / (e + 1.f);
}

// XOR-swizzled LDS addressing: row stride 512B, byte ^= (row&7)<<4.
#define SWZ(base, row, byte) ((base) + ((row) << 9) + ((byte) ^ (((row) & 7) << 4)))

// ---- prep: fragment-ordered bf16 W3 into ws ----
// frag(mt,kk), lane l: short8 of W3[kk*32+g*8+e][mt*16+c], at ws[(mt*8+kk)*64+l]
extern "C" __global__ void prep_kernel(const float* __restrict__ W3,
                                       short8* __restrict__ ws)
{
    const int tid = threadIdx.x;
    #pragma unroll
    for (int r = 0; r < 4; ++r) {
        const int idx = r*256 + tid;          // 0..1023
        const int l  = idx & 63;
        const int kk = (idx >> 6) & 7;
        const int mt = idx >> 9;
        const int g = (l >> 4) & 3, c = l & 15;
        short8 v;
        #pragma unroll
        for (int e = 0; e < 8; ++e)
            v[e] = f2bf(W3[(kk*32 + g*8 + e)*ND + mt*16 + c]);
        ws[idx] = v;
    }
}

// One block per batch element; 4 waves (256 threads); 2 blocks/CU.
// Best verified configuration (R15/R17, 206.6 us): scalars-in-LDS base +
// fused pass2 + LW1 cached once per stage in transient regs.
extern "C" __global__ void __launch_bounds__(256, 2)
node_kernel(const float* __restrict__ x_in,
            const float* __restrict__ W1, const float* __restrict__ b1,
            const float* __restrict__ W2, const float* __restrict__ b2,
            const float* __restrict__ W3, const float* __restrict__ b3,
            const short8* __restrict__ w3ws,
            float* __restrict__ out)
{
    __shared__ __align__(16) short LAA[33*256];   // A^T rows 0..31 + row32 = h1 (swizzled)
    __shared__ __align__(16) short LTs[33*256];   // Ts^T rows 0..31 + row32 = h2 (swizzled)
    __shared__ __align__(16) short8 W3L[16*64];   // fragment-ordered W3 (16 KB)
    __shared__ __align__(16) unsigned LW1[16*256];// packed bf16-pair W1 columns (16 KB)
    __shared__ __align__(16) float h2pre_s[NH];
    __shared__ __align__(16) float s2_s[NH];
    __shared__ __align__(16) float xs_s[4][ND];   // per-wave private
    __shared__ __align__(16) float xc_s[4][ND];   // per-wave private
    __shared__ __align__(16) float ksb[4][6][ND]; // per-wave private
    __shared__ __align__(16) float b3s[ND];       // b3 (read at c==0 each stage)
    __shared__ __align__(16) float w1ts[NH];      // W1 time row
    __shared__ __align__(16) float b1s[NH];
    __shared__ __align__(16) float b2s[NH];
    __shared__ float red[4][3];

    const int bid = blockIdx.x;
    const int tid = threadIdx.x;
    const int w = tid >> 6;        // wave id
    const int l = tid & 63;        // lane
    const int g = (tid >> 4) & 3;  // lane group
    const int c = tid & 15;        // lane&15

    char* LAc = (char*)LAA;
    char* LTc = (char*)LTs;
    const int swc = (c & 7) << 4;  // read-side swizzle

    // ---- one-time: W2 fragments into registers ----
    // frag (m,kk): value W2[kk*32+g*8+e][w*64+m*16+c]
    short8 w2f[4][8];
    #pragma unroll
    for (int m = 0; m < 4; ++m) {
        const int j = w*64 + m*16 + c;
        #pragma unroll
        for (int kk = 0; kk < 8; ++kk) {
            const int k0 = kk*32 + g*8;
            short8 f;
            #pragma unroll
            for (int e = 0; e < 8; ++e) f[e] = f2bf(W2[(k0+e)*NH + j]);
            w2f[m][kk] = f;
        }
    }
    // ---- one-time: W1 column tid packed bf16 into LDS; scalars into LDS ----
    {
        #pragma unroll
        for (int q = 0; q < 16; ++q) {
            unsigned lo = (unsigned)(unsigned short)f2bf(W1[(2*q)*NH + tid]);
            unsigned hi = (unsigned)(unsigned short)f2bf(W1[(2*q+1)*NH + tid]);
            LW1[q*256 + tid] = lo | (hi << 16);
        }
        w1ts[tid] = W1[32*NH + tid];
        b1s[tid]  = b1[tid];
        b2s[tid]  = b2[tid];
        if (tid < ND) b3s[tid] = b3[tid];
    }
    // ---- one-time: W3 fragments global->LDS (coalesced b128) ----
    #pragma unroll
    for (int r = 0; r < 4; ++r) W3L[r*256 + tid] = w3ws[r*256 + tid];
    // ---- J-phase: each wave owns one J tile ----
    const int mtJ = w >> 1, ntJ = w & 1;

    // ---- init per-wave ODE state ----
    if (l < ND) {
        const float xv = x_in[bid*ND + l];
        xc_s[w][l] = xv;
        xs_s[w][l] = xv;
    }
    __syncthreads();

    const float dt = 0.125f;
    float fr_acc = 0.f, ld_acc = 0.f, vf_acc = 0.f;
    const short8 zfrag = {0,0,0,0,0,0,0,0};

    for (int n = 0; n < NSTEPS; ++n) {
        const float t0 = (float)n * dt;
        for (int sg = 0; sg < 6; ++sg) {
            const float t_eff = 1.0f - (t0 + Ctab[sg]*dt);

            // ---- layer 1 + A-column build (own-wave xs; LW1 cached once) ----
            {
                unsigned w1c[16];
                #pragma unroll
                for (int q = 0; q < 16; ++q) w1c[q] = LW1[q*256 + tid];
                float pre = b1s[tid] + t_eff * w1ts[tid];
                #pragma unroll
                for (int q = 0; q < 8; ++q) {
                    f32x4 xq = *(const f32x4*)&xs_s[w][q*4];   // own-wave broadcast
                    unsigned p0 = w1c[2*q], p1 = w1c[2*q+1];
                    pre += xq[0]*bf_lo(p0) + xq[1]*bf_hi(p0)
                         + xq[2]*bf_lo(p1) + xq[3]*bf_hi(p1);
                }
                const float h1 = fast_tanh(pre);
                const float s1 = 1.f - h1*h1;
                #pragma unroll
                for (int q = 0; q < 16; ++q) {
                    unsigned p = w1c[q];
                    *(short*)SWZ(LAc, 2*q,   2*tid) = f2bf(bf_lo(p)*s1);
                    *(short*)SWZ(LAc, 2*q+1, 2*tid) = f2bf(bf_hi(p)*s1);
                }
                ((short*)LAA)[32*256 + tid] = f2bf(h1);  // row32 (swz==0)
            }
            __syncthreads();   // B1: A ready

            // ---- T^T pass 1: h1 column tile (nt=2) -> h2pre ----
            {
                f32x4 acc2[4];
                #pragma unroll
                for (int m = 0; m < 4; ++m) acc2[m] = (f32x4){0.f,0.f,0.f,0.f};
                #pragma unroll
                for (int kk = 0; kk < 8; ++kk) {
                    const int bo = kk*64 + g*16;
                    short8 fA2 = zfrag;                   // i=32 col: h1 only at c==0
                    if (c == 0) fA2 = *(const short8*)(LAc + (32 << 9) + bo);
                    #pragma unroll
                    for (int m = 0; m < 4; ++m)
                        acc2[m] = __builtin_amdgcn_mfma_f32_16x16x32_bf16(w2f[m][kk], fA2, acc2[m], 0,0,0);
                }
                if (c == 0) {
                    #pragma unroll
                    for (int m = 0; m < 4; ++m)
                        *(f32x4*)&h2pre_s[w*64 + m*16 + g*4] = acc2[m];
                }
            }
            const float h2 = fast_tanh(h2pre_s[tid] + b2s[tid]);  // own-wave LDS, in-order
            s2_s[tid] = 1.f - h2*h2;
            ((short*)LTs)[32*256 + tid] = f2bf(h2);               // row32 := h2

            // ---- T^T pass 2 (fused): tangent tiles, scale & store ----
            {
                f32x4 accT[4][2];
                #pragma unroll
                for (int m = 0; m < 4; ++m) {
                    accT[m][0] = (f32x4){0.f,0.f,0.f,0.f};
                    accT[m][1] = (f32x4){0.f,0.f,0.f,0.f};
                }
                #pragma unroll
                for (int kk = 0; kk < 8; ++kk) {
                    const int bo = kk*64 + g*16;
                    short8 fA0 = *(const short8*)(LAc + (( 0 + c) << 9) + (bo ^ swc));
                    short8 fA1 = *(const short8*)(LAc + ((16 + c) << 9) + (bo ^ swc));
                    #pragma unroll
                    for (int m = 0; m < 4; ++m) {
                        accT[m][0] = __builtin_amdgcn_mfma_f32_16x16x32_bf16(w2f[m][kk], fA0, accT[m][0], 0,0,0);
                        accT[m][1] = __builtin_amdgcn_mfma_f32_16x16x32_bf16(w2f[m][kk], fA1, accT[m][1], 0,0,0);
                    }
                }
                #pragma unroll
                for (int m = 0; m < 4; ++m) {
                    const int j0 = w*64 + m*16 + g*4;
                    f32x4 s2q = *(const f32x4*)&s2_s[j0];     // own-wave broadcast
                    #pragma unroll
                    for (int q = 0; q < 2; ++q) {
                        f32x4 v = accT[m][q] * s2q;
                        short4v p;
                        p[0] = f2bf(v[0]); p[1] = f2bf(v[1]); p[2] = f2bf(v[2]); p[3] = f2bf(v[3]);
                        *(short4v*)SWZ(LTc, q*16 + c, 2*j0) = p;
                    }
                }
            }
            __syncthreads();   // B2: Ts ready

            // ---- J-phase: 2 vf tiles (redundant) + 1 J tile (exclusive) ----
            f32x4 jva = (f32x4){0,0,0,0}, jvb = (f32x4){0,0,0,0}, jj = (f32x4){0,0,0,0};
            #pragma unroll
            for (int kk = 0; kk < 8; ++kk) {
                const int bo = kk*64 + g*16;
                short8 w3f0 = W3L[kk*64 + l];         // mt=0
                short8 w3f1 = W3L[(8+kk)*64 + l];     // mt=1
                short8 h2f = zfrag;
                if (c == 0) h2f = *(const short8*)(LTc + (32 << 9) + bo);
                jva = __builtin_amdgcn_mfma_f32_16x16x32_bf16(w3f0, h2f, jva, 0,0,0);
                jvb = __builtin_amdgcn_mfma_f32_16x16x32_bf16(w3f1, h2f, jvb, 0,0,0);
                short8 bJ = *(const short8*)(LTc + ((ntJ*16 + c) << 9) + (bo ^ swc));
                jj = __builtin_amdgcn_mfma_f32_16x16x32_bf16((mtJ == 0) ? w3f0 : w3f1, bJ, jj, 0,0,0);
            }

            const float wB = dt * Btab[sg];
            // ---- vf + per-wave ODE state update (same-wave, no barrier) ----
            if (c == 0) {
                const f32x4 b3a = *(const f32x4*)&b3s[g*4];      // from LDS
                const f32x4 b3b = *(const f32x4*)&b3s[16 + g*4];
                f32x4 dxa, dxb;
                dxa[0] = -(jva[0]+b3a[0]); dxa[1] = -(jva[1]+b3a[1]);
                dxa[2] = -(jva[2]+b3a[2]); dxa[3] = -(jva[3]+b3a[3]);
                dxb[0] = -(jvb[0]+b3b[0]); dxb[1] = -(jvb[1]+b3b[1]);
                dxb[2] = -(jvb[2]+b3b[2]); dxb[3] = -(jvb[3]+b3b[3]);
                *(f32x4*)&ksb[w][sg][g*4]      = dxa;
                *(f32x4*)&ksb[w][sg][16 + g*4] = dxb;
                if (w == 3)   // count vf once
                    vf_acc += wB * (dxa[0]*dxa[0]+dxa[1]*dxa[1]+dxa[2]*dxa[2]+dxa[3]*dxa[3]
                                  + dxb[0]*dxb[0]+dxb[1]*dxb[1]+dxb[2]*dxb[2]+dxb[3]*dxb[3]);
            }
            if (l < ND) {
                if (sg < 5) {
                    float v = xc_s[w][l];
                    for (int q = 0; q <= sg; ++q) v += dt * Atab[sg+1][q] * ksb[w][q][l];
                    xs_s[w][l] = v;
                } else {
                    float v = xc_s[w][l];
                    #pragma unroll
                    for (int q = 0; q < 6; ++q) v += dt * Btab[q] * ksb[w][q][l];
                    xc_s[w][l] = v;
                    xs_s[w][l] = v;
                }
            }
            // ---- frob / trace (exclusive J tile) ----
            fr_acc += wB * (jj[0]*jj[0]+jj[1]*jj[1]+jj[2]*jj[2]+jj[3]*jj[3]);
            if (mtJ == ntJ) {
                const int dd = c - g*4;
                if (dd >= 0 && dd < 4) {
                    float da = (dd==0)?jj[0]:(dd==1)?jj[1]:(dd==2)?jj[2]:jj[3];
                    ld_acc -= wB * da;
                }
            }
        }
    }

    // ---- final reduction of the three integrals ----
    float fr = fr_acc, ld = ld_acc, vf = vf_acc;
    #pragma unroll
    for (int off = 32; off > 0; off >>= 1) {
        fr += __shfl_down(fr, off, 64);
        ld += __shfl_down(ld, off, 64);
        vf += __shfl_down(vf, off, 64);
    }
    if (l == 0) { red[w][0] = fr; red[w][1] = ld; red[w][2] = vf; }
    __syncthreads();
    if (tid == 0) {
        float a = 0.f, b = 0.f, cq = 0.f;
        #pragma unroll
        for (int q = 0; q < 4; ++q) { a += red[q][0]; b += red[q][1]; cq += red[q][2]; }
        out[bid*35 + 32] = b;    // log_det = -∫tr
        out[bid*35 + 33] = cq;   // ∫|dxdt|^2
        out[bid*35 + 34] = a;    // ∫sum(J*J)
    }
    if (w == 3 && l < ND) out[bid*35 + l] = xc_s[3][l];
}

extern "C" void kernel_launch(void* const* d_in, const int* in_sizes, int n_in,
                              void* d_out, int out_size, void* d_ws, size_t ws_size,
                              hipStream_t stream) {
    const float* x  = (const float*)d_in[0];
    const float* W1 = (const float*)d_in[1];
    const float* b1 = (const float*)d_in[2];
    const float* W2 = (const float*)d_in[3];
    const float* b2 = (const float*)d_in[4];
    const float* W3 = (const float*)d_in[5];
    const float* b3 = (const float*)d_in[6];
    float* outp = (float*)d_out;
    hipLaunchKernelGGL(prep_kernel, dim3(1), dim3(256), 0, stream,
                       W3, (short8*)d_ws);
    hipLaunchKernelGGL(node_kernel, dim3(NB), dim3(256), 0, stream,
                       x, W1, b1, W2, b2, W3, b3, (const short8*)d_ws, outp);
}